// Round 1
// baseline (398.027 us; speedup 1.0000x reference)
//
#include <hip/hip_runtime.h>

// DiffNet fused forward: social diffusion (masked neighbor mean + 2-layer MLP)
// + dot-product prediction.  One wave per 4 batch rows; lane = feature index.
//
// Memory strategy: only gather the first `len` neighbor rows (reference reads
// all 50 and masks -> we halve HBM traffic).  8-deep unrolled independent
// gathers for latency hiding; masked tail group clamps the index to len-1 so
// the extra loads are L1 hits instead of a serial scalar remainder chain.
//
// Matvec strategy: W (2x64x64) staged once per block into LDS with row stride
// 68 dwords (16B-aligned ds_read_b128, banks spread: 68 mod 32 = 4 -> ~2-way).
// Each wave batches its 4 rows so one W read feeds 4 FMAs.  x[j] broadcast via
// v_readlane (VALU only, no LDS traffic -- __shfl would emit ds_bpermute and
// saturate the per-CU LDS pipe).

#define RPW 4          // rows per wave
#define WPB 4          // waves per block (256 threads)
#define WSTR 68        // padded W row stride in dwords

static __device__ __forceinline__ float readlane_f(float v, int l) {
    return __uint_as_float((unsigned)__builtin_amdgcn_readlane(__float_as_uint(v), l));
}

__global__ __launch_bounds__(256, 4)
void diffnet_fwd(const int* __restrict__ user_idx,
                 const int* __restrict__ product_idx,
                 const int* __restrict__ category_idx,
                 const int* __restrict__ neighbor_idx,
                 const int* __restrict__ neighbor_lens,
                 const float* __restrict__ user_emb,
                 const float* __restrict__ product_emb,
                 const float* __restrict__ category_emb,
                 const float* __restrict__ user_bias,
                 const float* __restrict__ product_bias,
                 const float* __restrict__ global_bias,
                 const float* __restrict__ W,
                 const float* __restrict__ bvec,
                 float* __restrict__ out)
{
    __shared__ float Wlds[128 * WSTR];   // 34,816 B -> 4 blocks/CU

    const int tid  = threadIdx.x;
    const int lane = tid & 63;
    const int wid  = tid >> 6;

    // ---- stage W (2*64*64 f32) into LDS, rows padded to 68 dwords ----
    #pragma unroll
    for (int it = 0; it < 8; ++it) {
        const int g   = it * 256 + tid;      // 0..2047 float4 groups
        const int row = g >> 4;              // l*64 + f
        const int jg  = g & 15;
        const float4 w4 = reinterpret_cast<const float4*>(W)[g];
        *reinterpret_cast<float4*>(&Wlds[row * WSTR + jg * 4]) = w4;
    }
    __syncthreads();

    const int wave_gid = blockIdx.x * WPB + wid;   // 0..4095
    const int row0 = wave_gid * RPW;               // 4 rows per wave

    const float gb = global_bias[0];
    const float b0 = bvec[lane];
    const float b1 = bvec[64 + lane];

    float u[RPW], m[RPW], comb[RPW], bias[RPW];
    int   lens[RPW];

    // ---- gather phase: u, combined product, biases, masked neighbor mean ----
    #pragma unroll
    for (int r = 0; r < RPW; ++r) {
        const int row = __builtin_amdgcn_readfirstlane(row0 + r);
        const int uid = user_idx[row];
        const int pid = product_idx[row];
        const int cid = category_idx[row];
        const int len = neighbor_lens[row];
        lens[r] = len;

        u[r]    = user_emb[(size_t)uid * 64 + lane];
        comb[r] = product_emb[(size_t)pid * 64 + lane]
                + 0.3f * category_emb[(size_t)cid * 64 + lane];
        bias[r] = gb + user_bias[uid] + product_bias[pid];

        const int* nptr = neighbor_idx + (size_t)row * 50;
        float nsum = 0.f;
        const int g8 = len >> 3;
        for (int g = 0; g < g8; ++g) {
            const int kb = g * 8;
            float a[8];
            #pragma unroll
            for (int i = 0; i < 8; ++i) {
                const int n = nptr[kb + i];
                a[i] = user_emb[(size_t)n * 64 + lane];
            }
            nsum += ((a[0] + a[1]) + (a[2] + a[3]))
                  + ((a[4] + a[5]) + (a[6] + a[7]));
        }
        const int kb = g8 * 8;
        if (kb < len) {              // masked tail group (clamped index = L1 hit)
            float a[8];
            #pragma unroll
            for (int i = 0; i < 8; ++i) {
                const int kk = kb + i;
                const int kc = (kk < len) ? kk : (len - 1);
                const int n  = nptr[kc];
                const float v = user_emb[(size_t)n * 64 + lane];
                a[i] = (kk < len) ? v : 0.f;
            }
            nsum += ((a[0] + a[1]) + (a[2] + a[3]))
                  + ((a[4] + a[5]) + (a[6] + a[7]));
        }
        const float cnt = (float)(len > 0 ? len : 1);
        m[r] = nsum / cnt;
    }

    // ---- 2-layer MLP, batched over the wave's 4 rows ----
    float x[RPW], acc[RPW];
    #pragma unroll
    for (int l = 0; l < 2; ++l) {
        #pragma unroll
        for (int r = 0; r < RPW; ++r) {
            x[r]   = u[r] + m[r];
            acc[r] = (l == 0) ? b0 : b1;
        }
        const float* wbase = &Wlds[(l * 64 + lane) * WSTR];
        #pragma unroll
        for (int jg = 0; jg < 16; ++jg) {
            const float4 w4 = *reinterpret_cast<const float4*>(wbase + jg * 4);
            float wv[4];
            wv[0] = w4.x; wv[1] = w4.y; wv[2] = w4.z; wv[3] = w4.w;
            #pragma unroll
            for (int i = 0; i < 4; ++i) {
                const int j = jg * 4 + i;
                #pragma unroll
                for (int r = 0; r < RPW; ++r) {
                    acc[r] = fmaf(readlane_f(x[r], j), wv[i], acc[r]);
                }
            }
        }
        #pragma unroll
        for (int r = 0; r < RPW; ++r)
            if (lens[r] > 0) u[r] = fmaxf(acc[r], 0.f);  // relu + has_nbr passthrough
    }

    // ---- prediction: dot(u, combined) + biases ----
    #pragma unroll
    for (int r = 0; r < RPW; ++r) {
        float v = u[r] * comb[r];
        #pragma unroll
        for (int off = 32; off > 0; off >>= 1)
            v += __shfl_xor(v, off, 64);
        if (lane == 0) out[row0 + r] = bias[r] + v;
    }
}

extern "C" void kernel_launch(void* const* d_in, const int* in_sizes, int n_in,
                              void* d_out, int out_size, void* d_ws, size_t ws_size,
                              hipStream_t stream) {
    const int*   user_idx      = (const int*)  d_in[0];
    const int*   product_idx   = (const int*)  d_in[1];
    const int*   category_idx  = (const int*)  d_in[2];
    const int*   neighbor_idx  = (const int*)  d_in[3];
    const int*   neighbor_lens = (const int*)  d_in[4];
    const float* user_emb      = (const float*)d_in[5];
    const float* product_emb   = (const float*)d_in[6];
    const float* category_emb  = (const float*)d_in[7];
    const float* user_bias     = (const float*)d_in[8];
    const float* product_bias  = (const float*)d_in[9];
    const float* global_bias   = (const float*)d_in[10];
    const float* W             = (const float*)d_in[11];
    const float* bvec          = (const float*)d_in[12];
    float* out = (float*)d_out;

    // 16384 rows / (4 rows * 4 waves per block) = 1024 blocks, exact cover
    diffnet_fwd<<<1024, 256, 0, stream>>>(
        user_idx, product_idx, category_idx, neighbor_idx, neighbor_lens,
        user_emb, product_emb, category_emb, user_bias, product_bias,
        global_bias, W, bvec, out);
}

// Round 2
// 395.880 us; speedup vs baseline: 1.0054x; 1.0054x over previous
//
#include <hip/hip_runtime.h>

// DiffNet fused forward — round 2: latency-bound -> BW-bound restructure.
//
// Gather engine: per row, ALL 50 neighbor indices are uniform scalar loads
// (s_load bursts, no vector round-trip), so the ~25 real 256-B embedding
// gathers issue back-to-back with zero dependent loads between them
// (~60 loads / 15 KB in flight per wave vs ~8 before). Tail lanes clamp the
// index to nbase[len-1] (scalar cselect, duplicate row -> L1 broadcast hit);
// uniform `len > 8g` guards skip whole groups without blocking issue
// (s_cbranch depends only on SGPR len, never on load data).
//
// MLP: W staged TRANSPOSED in LDS as WT[l][j][f], row stride 65 dwords ->
// both the transposing ds_writes and the per-j coalesced ds_reads are 2-way
// bank-aliased (free on wave64). x[j] broadcast via v_readlane (SGPR fma
// operand, zero LDS traffic). RPW=2: each WT read feeds 2 rows' FMAs.

#define WPB  4          // waves per block (256 threads)
#define RPW  2          // rows per wave
#define WSTR 65         // transposed W row stride in dwords (2-way banks)
#define KMAX 50

static __device__ __forceinline__ float readlane_f(float v, int l) {
    return __uint_as_float((unsigned)__builtin_amdgcn_readlane(__float_as_uint(v), l));
}

__global__ __launch_bounds__(256, 4)
void diffnet_fwd(const int* __restrict__ user_idx,
                 const int* __restrict__ product_idx,
                 const int* __restrict__ category_idx,
                 const int* __restrict__ neighbor_idx,
                 const int* __restrict__ neighbor_lens,
                 const float* __restrict__ user_emb,
                 const float* __restrict__ product_emb,
                 const float* __restrict__ category_emb,
                 const float* __restrict__ user_bias,
                 const float* __restrict__ product_bias,
                 const float* __restrict__ global_bias,
                 const float* __restrict__ W,
                 const float* __restrict__ bvec,
                 float* __restrict__ out)
{
    __shared__ float WT[2 * 64 * WSTR];   // 33,280 B -> 4 blocks/CU

    const int tid  = threadIdx.x;
    const int lane = tid & 63;

    // ---- stage W transposed: WT[l][j][f] = W[l][f][j] ----
    #pragma unroll
    for (int it = 0; it < 8; ++it) {
        const int g  = it * 256 + tid;            // 0..2047 float4 groups
        const float4 w4 = reinterpret_cast<const float4*>(W)[g];
        const int fr = g >> 4;                    // l*64 + f
        const int jg = g & 15;
        const int l  = fr >> 6;
        const int f  = fr & 63;
        float* base = &WT[l * 64 * WSTR + f];
        base[(4 * jg + 0) * WSTR] = w4.x;         // bank (4jg+i+f)%32: 2-way, free
        base[(4 * jg + 1) * WSTR] = w4.y;
        base[(4 * jg + 2) * WSTR] = w4.z;
        base[(4 * jg + 3) * WSTR] = w4.w;
    }
    __syncthreads();

    const int wid  = tid >> 6;
    const int row0 = (blockIdx.x * WPB + wid) * RPW;

    // ---- scalar phase: both rows' indices/lens up front (s_load bursts) ----
    int rows[RPW], lens[RPW], uids[RPW], pids[RPW], cids[RPW];
    #pragma unroll
    for (int r = 0; r < RPW; ++r) {
        const int row = __builtin_amdgcn_readfirstlane(row0 + r);
        rows[r] = row;
        lens[r] = neighbor_lens[row];
        uids[r] = user_idx[row];
        pids[r] = product_idx[row];
        cids[r] = category_idx[row];
    }
    const float gb = global_bias[0];

    // ---- independent vector gathers for u / combined product; scalar biases ----
    float u[RPW], comb[RPW], bias[RPW], m[RPW];
    #pragma unroll
    for (int r = 0; r < RPW; ++r) {
        u[r]    = user_emb[((size_t)uids[r] << 6) + lane];
        comb[r] = product_emb[((size_t)pids[r] << 6) + lane]
                + 0.3f * category_emb[((size_t)cids[r] << 6) + lane];
        bias[r] = gb + user_bias[uids[r]] + product_bias[pids[r]];
    }

    // ---- neighbor mean: index prefetch in SGPRs, gathers fully pipelined ----
    #pragma unroll
    for (int r = 0; r < RPW; ++r) {
        const int len = lens[r];
        float nsum = 0.f;
        if (len > 0) {                            // wave-uniform branch
            const int* nbase = neighbor_idx + rows[r] * KMAX;
            const int  last  = nbase[len - 1];    // scalar load
            float tsum = 0.f;
            #pragma unroll
            for (int g = 0; g < 6; ++g) {         // groups of 8, k = 8g..8g+7
                if (len > g * 8) {                // uniform guard, SGPR-only
                    float a[8];
                    #pragma unroll
                    for (int i = 0; i < 8; ++i) {
                        const int kk = g * 8 + i;
                        const int n0 = nbase[kk];             // s_load (always valid)
                        const int n  = (kk < len) ? n0 : last; // s_cselect clamp
                        const float v = user_emb[((size_t)n << 6) + lane];
                        a[i] = (kk < len) ? v : 0.f;
                    }
                    tsum += ((a[0] + a[1]) + (a[2] + a[3]))
                          + ((a[4] + a[5]) + (a[6] + a[7]));
                }
            }
            if (len > 48) {                       // tail pair k = 48,49
                const int n0 = nbase[48];
                const int n1 = nbase[49];
                const int nb = (49 < len) ? n1 : last;
                const float va = user_emb[((size_t)n0 << 6) + lane];
                float       vb = user_emb[((size_t)nb << 6) + lane];
                vb = (49 < len) ? vb : 0.f;
                tsum += va + vb;
            }
            nsum = tsum / (float)len;
        }
        m[r] = nsum;
    }

    // ---- 2-layer MLP: one WT read feeds both rows ----
    const float bl0 = bvec[lane];
    const float bl1 = bvec[64 + lane];
    #pragma unroll
    for (int l = 0; l < 2; ++l) {
        const float x0 = u[0] + m[0];
        const float x1 = u[1] + m[1];
        float acc0 = l ? bl1 : bl0;
        float acc1 = acc0;
        const float* wt = &WT[l * 64 * WSTR + lane];
        #pragma unroll
        for (int j = 0; j < 64; ++j) {
            const float wv = wt[j * WSTR];        // coalesced, 2-way banks
            acc0 = fmaf(readlane_f(x0, j), wv, acc0);
            acc1 = fmaf(readlane_f(x1, j), wv, acc1);
        }
        if (lens[0] > 0) u[0] = fmaxf(acc0, 0.f); // relu + has_nbr passthrough
        if (lens[1] > 0) u[1] = fmaxf(acc1, 0.f);
    }

    // ---- prediction: dot(u, comb) + biases ----
    #pragma unroll
    for (int r = 0; r < RPW; ++r) {
        float v = u[r] * comb[r];
        #pragma unroll
        for (int off = 32; off; off >>= 1)
            v += __shfl_xor(v, off, 64);
        if (lane == 0) out[rows[r]] = bias[r] + v;
    }
}

extern "C" void kernel_launch(void* const* d_in, const int* in_sizes, int n_in,
                              void* d_out, int out_size, void* d_ws, size_t ws_size,
                              hipStream_t stream) {
    const int*   user_idx      = (const int*)  d_in[0];
    const int*   product_idx   = (const int*)  d_in[1];
    const int*   category_idx  = (const int*)  d_in[2];
    const int*   neighbor_idx  = (const int*)  d_in[3];
    const int*   neighbor_lens = (const int*)  d_in[4];
    const float* user_emb      = (const float*)d_in[5];
    const float* product_emb   = (const float*)d_in[6];
    const float* category_emb  = (const float*)d_in[7];
    const float* user_bias     = (const float*)d_in[8];
    const float* product_bias  = (const float*)d_in[9];
    const float* global_bias   = (const float*)d_in[10];
    const float* W             = (const float*)d_in[11];
    const float* bvec          = (const float*)d_in[12];
    float* out = (float*)d_out;

    // 16384 rows / (2 rows * 4 waves per block) = 2048 blocks, exact cover
    diffnet_fwd<<<2048, 256, 0, stream>>>(
        user_idx, product_idx, category_idx, neighbor_idx, neighbor_lens,
        user_emb, product_emb, category_emb, user_bias, product_bias,
        global_bias, W, bvec, out);
}